// Round 3
// baseline (117.334 us; speedup 1.0000x reference)
//
#include <hip/hip_runtime.h>
#include <hip/hip_bf16.h>

// Problem constants
#define BDIM 1024
#define NCOL 1152      // 9 heads * 64 * 2 (q,k)
#define HEADS 9
#define HID 64
#define SLEN 512
#define BATCH 16

typedef __attribute__((ext_vector_type(8))) short bf16x8;
typedef __attribute__((ext_vector_type(4))) float f32x4;
typedef __attribute__((ext_vector_type(4))) unsigned short u16x4;

static __device__ __forceinline__ unsigned short f2bf(float f) {
    union { float f; unsigned int u; } x; x.f = f;
    unsigned int u = x.u;
    unsigned int r = (u + 0x7fffu + ((u >> 16) & 1u)) >> 16;
    return (unsigned short)r;
}

// packed f32x2 -> bf16x2 (RNE), single HW instruction on gfx950
static __device__ __forceinline__ unsigned int pk2bf(float lo, float hi) {
    unsigned int r;
    asm("v_cvt_pk_bf16_f32 %0, %1, %2" : "=v"(r) : "v"(lo), "v"(hi));
    return r;
}

#define GLOAD_LDS16(g, l)                                                     \
    __builtin_amdgcn_global_load_lds(                                         \
        (const __attribute__((address_space(1))) unsigned int*)(g),           \
        (__attribute__((address_space(3))) unsigned int*)(l), 16, 0, 0)

// ---------------------------------------------------------------------------
// Prep kernel: blocks [0,1152): W [1024][1152] f32 -> Wt [1152][1024] bf16
//              blocks [1152,1216): RoPE table sctab[512][32] of {sin,cos}
// ---------------------------------------------------------------------------
__global__ __launch_bounds__(256) void prep_kernel(const float* __restrict__ W,
                                                   unsigned short* __restrict__ Wt,
                                                   float* __restrict__ sctab) {
    __shared__ float tile[32][33];
    const int b = blockIdx.x;
    if (b < 1152) {
        const int tx = threadIdx.x & 31;
        const int ty = threadIdx.x >> 5;      // 0..7
        const int nb = (b % 36) * 32;         // over NCOL
        const int kb = (b / 36) * 32;         // over BDIM
#pragma unroll
        for (int i = 0; i < 4; ++i) {
            int k = kb + ty + i * 8;
            tile[ty + i * 8][tx] = W[(size_t)k * NCOL + nb + tx];
        }
        __syncthreads();
#pragma unroll
        for (int i = 0; i < 4; ++i) {
            int n = nb + ty + i * 8;
            Wt[(size_t)n * BDIM + kb + tx] = f2bf(tile[tx][ty + i * 8]);
        }
    } else {
        int idx = (b - 1152) * 256 + threadIdx.x;   // 0..16383
        int s = idx >> 5, j = idx & 31;
        float inv = powf(10000.0f, -(float)(2 * j) / (float)HID);
        float ang = (float)s * inv;
        sctab[idx * 2]     = sinf(ang);
        sctab[idx * 2 + 1] = cosf(ang);
    }
}

// ---------------------------------------------------------------------------
// Projection GEMM (8192x1024 f32-A @ 1024x1152 bf16-B) + bias + RoPE
// -> qk bf16 [16][9][2][512][64]
// A staged f32 via global_load_lds (XOR-swizzled source, swizzled read),
// converted to bf16 at fragment read (v_cvt_pk_bf16_f32).
// MFMA operand-swapped: acc regs run along the column (d) dimension.
// ---------------------------------------------------------------------------
__global__ __launch_bounds__(256) void proj_rope_kernel(
    const float* __restrict__ hidden,        // [8192][1024] f32
    const unsigned short* __restrict__ Wt,   // [1152][1024] bf16
    const float* __restrict__ bias,          // [1152]
    const float4* __restrict__ sctab4,       // [512][16] {s,c,s,c}
    unsigned short* __restrict__ qk)         // [16][9][2][512][64] bf16
{
    __shared__ __attribute__((aligned(16))) float As[128 * 32];           // 16 KB
    __shared__ __attribute__((aligned(16))) unsigned short Bs[128 * 32];  // 8 KB

    const int t = threadIdx.x;
    const int m0 = blockIdx.x * 128;
    const int n0 = blockIdx.y * 128;
    const int wid = t >> 6, lane = t & 63;
    const int wr = wid >> 1, wc = wid & 1;
    const int lrow = lane & 15;
    const int lk = lane >> 4;                 // 0..3

    // A staging: issue i covers rows arow + i*32; 128B/row; swizzled source col
    const int arow = wid * 8 + (lane >> 3);
    const int acolb = (((lane & 7) << 4)) ^ (((lane >> 3) & 7) << 4);
    const float* gA = hidden + (size_t)(m0 + arow) * BDIM + (acolb >> 2);
    // B staging: issue j covers rows brow + j*64; 64B/row; swizzled source col
    const int brow = wid * 16 + (lane >> 2);
    const int bcolb = (((lane & 3) << 4)) ^ (((lane >> 3) & 3) << 4);
    const unsigned short* gB = Wt + (size_t)(n0 + brow) * BDIM + (bcolb >> 1);

    float* lA = As + wid * 256;               // wave chunk, bytes wid*1024
    unsigned short* lB = Bs + wid * 512;

    f32x4 acc[4][4] = {};                     // [ni][mi], regs along n/d

    for (int k0 = 0; k0 < BDIM; k0 += 32) {
        GLOAD_LDS16(gA + k0,             lA);
        GLOAD_LDS16(gA + k0 + 32 * BDIM, lA + 1024);
        GLOAD_LDS16(gA + k0 + 64 * BDIM, lA + 2048);
        GLOAD_LDS16(gA + k0 + 96 * BDIM, lA + 3072);
        GLOAD_LDS16(gB + k0,             lB);
        GLOAD_LDS16(gB + k0 + 64 * BDIM, lB + 2048);
        __syncthreads();

        bf16x8 af[4], bfr[4];
#pragma unroll
        for (int mi = 0; mi < 4; ++mi) {
            int row = wr * 64 + mi * 16 + lrow;
            int sw = (row & 7) << 4;
            const char* base = (const char*)As + row * 128;
            f32x4 x0 = *reinterpret_cast<const f32x4*>(base + ((lk * 32) ^ sw));
            f32x4 x1 = *reinterpret_cast<const f32x4*>(base + ((lk * 32 + 16) ^ sw));
            union { unsigned int u[4]; bf16x8 v; } cv;
            cv.u[0] = pk2bf(x0[0], x0[1]);
            cv.u[1] = pk2bf(x0[2], x0[3]);
            cv.u[2] = pk2bf(x1[0], x1[1]);
            cv.u[3] = pk2bf(x1[2], x1[3]);
            af[mi] = cv.v;
        }
#pragma unroll
        for (int ni = 0; ni < 4; ++ni) {
            int row = wc * 64 + ni * 16 + lrow;
            int sw = ((lrow >> 1) & 3) << 4;
            bfr[ni] = *reinterpret_cast<const bf16x8*>(
                (const char*)Bs + row * 64 + ((lk * 16) ^ sw));
        }
#pragma unroll
        for (int ni = 0; ni < 4; ++ni)
#pragma unroll
            for (int mi = 0; mi < 4; ++mi)
                acc[ni][mi] = __builtin_amdgcn_mfma_f32_16x16x32_bf16(
                    bfr[ni], af[mi], acc[ni][mi], 0, 0, 0);
        __syncthreads();
    }

    // epilogue: bias + RoPE (in-register pairs) + ushort4 stores
    const float4* bias4 = (const float4*)bias;
#pragma unroll
    for (int ni = 0; ni < 4; ++ni) {
        int cb = n0 + wc * 64 + ni * 16 + lk * 4;   // 4 consecutive columns
        float4 bv = bias4[cb >> 2];
        int h = cb >> 7;
        int qki = (cb >> 6) & 1;
        int d0 = cb & 63;                            // multiple of 4
#pragma unroll
        for (int mi = 0; mi < 4; ++mi) {
            int m = m0 + wr * 64 + mi * 16 + lrow;
            int bi = m >> 9, s = m & 511;
            float4 sc = sctab4[s * 16 + (d0 >> 2)];  // {sin j, cos j, sin j+1, cos j+1}
            f32x4 a = acc[ni][mi];
            float v0 = a[0] + bv.x, v1 = a[1] + bv.y;
            float v2 = a[2] + bv.z, v3 = a[3] + bv.w;
            u16x4 p;
            p[0] = f2bf(v0 * sc.y - v1 * sc.x);
            p[1] = f2bf(v1 * sc.y + v0 * sc.x);
            p[2] = f2bf(v2 * sc.w - v3 * sc.z);
            p[3] = f2bf(v3 * sc.w + v2 * sc.z);
            *reinterpret_cast<u16x4*>(
                qk + ((((size_t)bi * HEADS + h) * 2 + qki) * SLEN + s) * HID + d0) = p;
        }
    }
}

// ---------------------------------------------------------------------------
// logits[b,h,m,n] = (q.k * pad - (1-pad)*1e12) / 8
// per (b,h): 512x64 @ 64x512; grid (4,4,144), 128x128 tiles
// MFMA operand-swapped: acc regs run along n -> float4 stores.
// ---------------------------------------------------------------------------
__global__ __launch_bounds__(256) void logits_kernel(
    const unsigned short* __restrict__ qkbuf,  // [16][9][2][512][64] bf16
    const float* __restrict__ mask,            // [16][512]
    float* __restrict__ out)                   // [16][9][512][512]
{
    __shared__ __attribute__((aligned(16))) unsigned short Qs[128 * 72];
    __shared__ __attribute__((aligned(16))) unsigned short Ks[128 * 72];

    const int t = threadIdx.x;
    const int bz = blockIdx.z;                 // b*9 + h
    const int bi = bz / 9;
    const int m0 = blockIdx.x * 128, n0 = blockIdx.y * 128;

    const unsigned short* Qg = qkbuf + ((size_t)bz * 2 + 0) * SLEN * HID + (size_t)m0 * HID;
    const unsigned short* Kg = qkbuf + ((size_t)bz * 2 + 1) * SLEN * HID + (size_t)n0 * HID;

#pragma unroll
    for (int i = 0; i < 4; ++i) {
        int e = t + i * 256;                   // 0..1023
        int row = e >> 3, c = e & 7;           // 8 x 16B per 64-elem row
        *reinterpret_cast<uint4*>(&Qs[row * 72 + c * 8]) =
            *reinterpret_cast<const uint4*>(Qg + (size_t)row * HID + c * 8);
        *reinterpret_cast<uint4*>(&Ks[row * 72 + c * 8]) =
            *reinterpret_cast<const uint4*>(Kg + (size_t)row * HID + c * 8);
    }
    __syncthreads();

    const int wid = t >> 6, lane = t & 63;
    const int wr = wid >> 1, wc = wid & 1;
    const int lrow = lane & 15;
    const int lk = lane >> 4;

    f32x4 acc[4][4] = {};                      // [ni][mi]
#pragma unroll
    for (int kk = 0; kk < 2; ++kk) {
        bf16x8 af[4], bfr[4];
#pragma unroll
        for (int mi = 0; mi < 4; ++mi)
            af[mi] = *reinterpret_cast<const bf16x8*>(
                &Qs[(wr * 64 + mi * 16 + lrow) * 72 + kk * 32 + lk * 8]);
#pragma unroll
        for (int ni = 0; ni < 4; ++ni)
            bfr[ni] = *reinterpret_cast<const bf16x8*>(
                &Ks[(wc * 64 + ni * 16 + lrow) * 72 + kk * 32 + lk * 8]);
#pragma unroll
        for (int ni = 0; ni < 4; ++ni)
#pragma unroll
            for (int mi = 0; mi < 4; ++mi)
                acc[ni][mi] = __builtin_amdgcn_mfma_f32_16x16x32_bf16(
                    bfr[ni], af[mi], acc[ni][mi], 0, 0, 0);
    }

#pragma unroll
    for (int ni = 0; ni < 4; ++ni) {
        int nb = n0 + wc * 64 + ni * 16 + lk * 4;    // 4 consecutive n
        float4 pv = *reinterpret_cast<const float4*>(mask + bi * SLEN + nb);
        float sx = (1.0f - pv.x) * 1000000000000.0f;
        float sy = (1.0f - pv.y) * 1000000000000.0f;
        float sz = (1.0f - pv.z) * 1000000000000.0f;
        float sw = (1.0f - pv.w) * 1000000000000.0f;
#pragma unroll
        for (int mi = 0; mi < 4; ++mi) {
            int m = m0 + wr * 64 + mi * 16 + lrow;
            f32x4 a = acc[ni][mi];
            f32x4 o;
            o[0] = (a[0] * pv.x - sx) * 0.125f;
            o[1] = (a[1] * pv.y - sy) * 0.125f;
            o[2] = (a[2] * pv.z - sz) * 0.125f;
            o[3] = (a[3] * pv.w - sw) * 0.125f;
            *reinterpret_cast<f32x4*>(out + ((size_t)bz * SLEN + m) * SLEN + nb) = o;
        }
    }
}

// ---------------------------------------------------------------------------
extern "C" void kernel_launch(void* const* d_in, const int* in_sizes, int n_in,
                              void* d_out, int out_size, void* d_ws, size_t ws_size,
                              hipStream_t stream) {
    const float* hidden = (const float*)d_in[0];   // 16*512*1024
    const float* mask   = (const float*)d_in[1];   // 16*512
    const float* W      = (const float*)d_in[2];   // 1024*1152
    const float* bias   = (const float*)d_in[3];   // 1152
    float* out = (float*)d_out;

    char* ws = (char*)d_ws;
    unsigned short* Wt = (unsigned short*)ws;                 // 2,359,296 B
    float* sctab = (float*)(ws + 2359296);                    //   131,072 B
    unsigned short* qk = (unsigned short*)(ws + 2359296 + 131072); // 18,874,368 B

    prep_kernel<<<1216, 256, 0, stream>>>(W, Wt, sctab);
    proj_rope_kernel<<<dim3(64, 9), 256, 0, stream>>>(
        hidden, Wt, bias, (const float4*)sctab, qk);
    logits_kernel<<<dim3(4, 4, BATCH * HEADS), 256, 0, stream>>>(qk, mask, out);
}

// Round 4
// 94.043 us; speedup vs baseline: 1.2477x; 1.2477x over previous
//
#include <hip/hip_runtime.h>
#include <hip/hip_bf16.h>

// Problem constants
#define BDIM 1024
#define NCOL 1152      // 9 heads * 64 * 2 (q,k)
#define HEADS 9
#define HID 64
#define SLEN 512
#define BATCH 16

typedef __attribute__((ext_vector_type(8))) short bf16x8;
typedef __attribute__((ext_vector_type(8))) unsigned short u16x8;
typedef __attribute__((ext_vector_type(4))) float f32x4;
typedef __attribute__((ext_vector_type(4))) unsigned short u16x4;

static __device__ __forceinline__ unsigned short f2bf(float f) {
    union { float f; unsigned int u; } x; x.f = f;
    unsigned int u = x.u;
    unsigned int r = (u + 0x7fffu + ((u >> 16) & 1u)) >> 16;
    return (unsigned short)r;
}

#define GLOAD_LDS16(g, l)                                                     \
    __builtin_amdgcn_global_load_lds(                                         \
        (const __attribute__((address_space(1))) unsigned int*)(g),           \
        (__attribute__((address_space(3))) unsigned int*)(l), 16, 0, 0)

// ---------------------------------------------------------------------------
// Prep kernel (fused):
//   blocks [0,4096):     hidden f32 -> Ab bf16 (2048 elems/block)
//   blocks [4096,5248):  W [1024][1152] f32 -> Wt [1152][1024] bf16
//   blocks [5248,5312):  RoPE table sctab[512][32] of {sin,cos}
// ---------------------------------------------------------------------------
__global__ __launch_bounds__(256) void prep_kernel(const float* __restrict__ hidden,
                                                   const float* __restrict__ W,
                                                   unsigned short* __restrict__ Ab,
                                                   unsigned short* __restrict__ Wt,
                                                   float* __restrict__ sctab) {
    __shared__ float tile[32][33];
    const int b = blockIdx.x;
    if (b < 4096) {
        int i = (b * 256 + threadIdx.x) * 8;
        float4 a = *reinterpret_cast<const float4*>(hidden + i);
        float4 c = *reinterpret_cast<const float4*>(hidden + i + 4);
        u16x8 p;
        p[0] = f2bf(a.x); p[1] = f2bf(a.y); p[2] = f2bf(a.z); p[3] = f2bf(a.w);
        p[4] = f2bf(c.x); p[5] = f2bf(c.y); p[6] = f2bf(c.z); p[7] = f2bf(c.w);
        *reinterpret_cast<u16x8*>(Ab + i) = p;
    } else if (b < 5248) {
        const int bb = b - 4096;
        const int tx = threadIdx.x & 31;
        const int ty = threadIdx.x >> 5;      // 0..7
        const int nb = (bb % 36) * 32;        // over NCOL
        const int kb = (bb / 36) * 32;        // over BDIM
#pragma unroll
        for (int i = 0; i < 4; ++i) {
            int k = kb + ty + i * 8;
            tile[ty + i * 8][tx] = W[(size_t)k * NCOL + nb + tx];
        }
        __syncthreads();
#pragma unroll
        for (int i = 0; i < 4; ++i) {
            int n = nb + ty + i * 8;
            Wt[(size_t)n * BDIM + kb + tx] = f2bf(tile[tx][ty + i * 8]);
        }
    } else {
        int idx = (b - 5248) * 256 + threadIdx.x;   // 0..16383
        int s = idx >> 5, j = idx & 31;
        float inv = powf(10000.0f, -(float)(2 * j) / (float)HID);
        float ang = (float)s * inv;
        sctab[idx * 2]     = sinf(ang);
        sctab[idx * 2 + 1] = cosf(ang);
    }
}

// ---------------------------------------------------------------------------
// Projection GEMM (8192x1024 @ 1024x1152, both bf16) + bias + RoPE
// -> qk bf16 [16][9][2][512][64]
// 128x128 tile, BK=32, 2-phase double-buffered LDS (one barrier/iter),
// XOR-swizzled tiles (key=(row^(row>>2))&3 on 16B slots; source-side swizzle
// for global_load_lds, swizzled ds_read) -> 2-way banks (free).
// MFMA operand-swapped: acc regs run along the column (d) dimension.
// ---------------------------------------------------------------------------
__global__ __launch_bounds__(256) void proj_rope_kernel(
    const unsigned short* __restrict__ Ab,   // [8192][1024] bf16
    const unsigned short* __restrict__ Wt,   // [1152][1024] bf16
    const float* __restrict__ bias,          // [1152]
    const float4* __restrict__ sctab4,       // [512][16] {s,c,s,c}
    unsigned short* __restrict__ qk)         // [16][9][2][512][64] bf16
{
    __shared__ __attribute__((aligned(16))) unsigned short As[2][128 * 32]; // 16 KB
    __shared__ __attribute__((aligned(16))) unsigned short Bs[2][128 * 32]; // 16 KB

    const int t = threadIdx.x;
    const int m0 = blockIdx.x * 128;
    const int n0 = blockIdx.y * 128;
    const int wid = t >> 6, lane = t & 63;
    const int wr = wid >> 1, wc = wid & 1;
    const int lrow = lane & 15;
    const int lk = lane >> 4;                 // 0..3

    // --- staging: 16 rows per wave per issue, 4 lanes x 16B per row.
    const int rowoff = lane >> 2;                         // 0..15
    const int skey = (rowoff ^ (rowoff >> 2)) & 3;        // swizzle key
    const int sslot = (lane & 3) ^ skey;                  // source 16B slot
    const int srow = wid * 16 + rowoff;
    const unsigned short* gA = Ab + (size_t)(m0 + srow) * BDIM + sslot * 8;
    const unsigned short* gB = Wt + (size_t)(n0 + srow) * BDIM + sslot * 8;
    const int ldst = wid * 512;               // wave chunk, elems

#define STAGE(buf, k0)                                                        \
    do {                                                                      \
        GLOAD_LDS16(gA + (k0),              &As[buf][ldst]);                  \
        GLOAD_LDS16(gA + (k0) + 64 * BDIM,  &As[buf][ldst + 2048]);           \
        GLOAD_LDS16(gB + (k0),              &Bs[buf][ldst]);                  \
        GLOAD_LDS16(gB + (k0) + 64 * BDIM,  &Bs[buf][ldst + 2048]);           \
    } while (0)

    // --- fragment read swizzle (row & 15 == lrow for all fragments)
    const int rkey = (lrow ^ (lrow >> 2)) & 3;
    const int fslot = ((lk ^ rkey) & 3) << 4;             // byte offset in row

    f32x4 acc[4][4] = {};                     // [ni][mi], regs along n/d

    STAGE(0, 0);
    __syncthreads();

    for (int it = 0; it < 32; ++it) {
        const int cur = it & 1;
        if (it < 31) STAGE(cur ^ 1, (it + 1) * 32);

        const char* Ac = (const char*)As[cur];
        const char* Bc = (const char*)Bs[cur];
        bf16x8 af[4], bfr[4];
#pragma unroll
        for (int mi = 0; mi < 4; ++mi)
            af[mi] = *reinterpret_cast<const bf16x8*>(
                Ac + (wr * 64 + mi * 16 + lrow) * 64 + fslot);
#pragma unroll
        for (int ni = 0; ni < 4; ++ni)
            bfr[ni] = *reinterpret_cast<const bf16x8*>(
                Bc + (wc * 64 + ni * 16 + lrow) * 64 + fslot);
#pragma unroll
        for (int ni = 0; ni < 4; ++ni)
#pragma unroll
            for (int mi = 0; mi < 4; ++mi)
                acc[ni][mi] = __builtin_amdgcn_mfma_f32_16x16x32_bf16(
                    bfr[ni], af[mi], acc[ni][mi], 0, 0, 0);
        __syncthreads();
    }
#undef STAGE

    // epilogue: bias + RoPE (in-register pairs) + ushort4 stores
    const float4* bias4 = (const float4*)bias;
#pragma unroll
    for (int ni = 0; ni < 4; ++ni) {
        int cb = n0 + wc * 64 + ni * 16 + lk * 4;   // 4 consecutive columns
        float4 bv = bias4[cb >> 2];
        int h = cb >> 7;
        int qki = (cb >> 6) & 1;
        int d0 = cb & 63;                            // multiple of 4
#pragma unroll
        for (int mi = 0; mi < 4; ++mi) {
            int m = m0 + wr * 64 + mi * 16 + lrow;
            int bi = m >> 9, s = m & 511;
            float4 sc = sctab4[s * 16 + (d0 >> 2)];  // {sin j, cos j, sin j+1, cos j+1}
            f32x4 a = acc[ni][mi];
            float v0 = a[0] + bv.x, v1 = a[1] + bv.y;
            float v2 = a[2] + bv.z, v3 = a[3] + bv.w;
            u16x4 p;
            p[0] = f2bf(v0 * sc.y - v1 * sc.x);
            p[1] = f2bf(v1 * sc.y + v0 * sc.x);
            p[2] = f2bf(v2 * sc.w - v3 * sc.z);
            p[3] = f2bf(v3 * sc.w + v2 * sc.z);
            *reinterpret_cast<u16x4*>(
                qk + ((((size_t)bi * HEADS + h) * 2 + qki) * SLEN + s) * HID + d0) = p;
        }
    }
}

// ---------------------------------------------------------------------------
// logits[b,h,m,n] = (q.k * pad - (1-pad)*1e12) / 8
// per (b,h): 512x64 @ 64x512; grid (4,4,144), 128x128 tiles
// MFMA operand-swapped: acc regs run along n -> float4 stores.
// ---------------------------------------------------------------------------
__global__ __launch_bounds__(256) void logits_kernel(
    const unsigned short* __restrict__ qkbuf,  // [16][9][2][512][64] bf16
    const float* __restrict__ mask,            // [16][512]
    float* __restrict__ out)                   // [16][9][512][512]
{
    __shared__ __attribute__((aligned(16))) unsigned short Qs[128 * 72];
    __shared__ __attribute__((aligned(16))) unsigned short Ks[128 * 72];

    const int t = threadIdx.x;
    const int bz = blockIdx.z;                 // b*9 + h
    const int bi = bz / 9;
    const int m0 = blockIdx.x * 128, n0 = blockIdx.y * 128;

    const unsigned short* Qg = qkbuf + ((size_t)bz * 2 + 0) * SLEN * HID + (size_t)m0 * HID;
    const unsigned short* Kg = qkbuf + ((size_t)bz * 2 + 1) * SLEN * HID + (size_t)n0 * HID;

#pragma unroll
    for (int i = 0; i < 4; ++i) {
        int e = t + i * 256;                   // 0..1023
        int row = e >> 3, c = e & 7;           // 8 x 16B per 64-elem row
        *reinterpret_cast<uint4*>(&Qs[row * 72 + c * 8]) =
            *reinterpret_cast<const uint4*>(Qg + (size_t)row * HID + c * 8);
        *reinterpret_cast<uint4*>(&Ks[row * 72 + c * 8]) =
            *reinterpret_cast<const uint4*>(Kg + (size_t)row * HID + c * 8);
    }
    __syncthreads();

    const int wid = t >> 6, lane = t & 63;
    const int wr = wid >> 1, wc = wid & 1;
    const int lrow = lane & 15;
    const int lk = lane >> 4;

    f32x4 acc[4][4] = {};                      // [ni][mi]
#pragma unroll
    for (int kk = 0; kk < 2; ++kk) {
        bf16x8 af[4], bfr[4];
#pragma unroll
        for (int mi = 0; mi < 4; ++mi)
            af[mi] = *reinterpret_cast<const bf16x8*>(
                &Qs[(wr * 64 + mi * 16 + lrow) * 72 + kk * 32 + lk * 8]);
#pragma unroll
        for (int ni = 0; ni < 4; ++ni)
            bfr[ni] = *reinterpret_cast<const bf16x8*>(
                &Ks[(wc * 64 + ni * 16 + lrow) * 72 + kk * 32 + lk * 8]);
#pragma unroll
        for (int ni = 0; ni < 4; ++ni)
#pragma unroll
            for (int mi = 0; mi < 4; ++mi)
                acc[ni][mi] = __builtin_amdgcn_mfma_f32_16x16x32_bf16(
                    bfr[ni], af[mi], acc[ni][mi], 0, 0, 0);
    }

#pragma unroll
    for (int ni = 0; ni < 4; ++ni) {
        int nb = n0 + wc * 64 + ni * 16 + lk * 4;    // 4 consecutive n
        float4 pv = *reinterpret_cast<const float4*>(mask + bi * SLEN + nb);
        float sx = (1.0f - pv.x) * 1000000000000.0f;
        float sy = (1.0f - pv.y) * 1000000000000.0f;
        float sz = (1.0f - pv.z) * 1000000000000.0f;
        float sw = (1.0f - pv.w) * 1000000000000.0f;
#pragma unroll
        for (int mi = 0; mi < 4; ++mi) {
            int m = m0 + wr * 64 + mi * 16 + lrow;
            f32x4 a = acc[ni][mi];
            f32x4 o;
            o[0] = (a[0] * pv.x - sx) * 0.125f;
            o[1] = (a[1] * pv.y - sy) * 0.125f;
            o[2] = (a[2] * pv.z - sz) * 0.125f;
            o[3] = (a[3] * pv.w - sw) * 0.125f;
            *reinterpret_cast<f32x4*>(out + ((size_t)bz * SLEN + m) * SLEN + nb) = o;
        }
    }
}

// ---------------------------------------------------------------------------
extern "C" void kernel_launch(void* const* d_in, const int* in_sizes, int n_in,
                              void* d_out, int out_size, void* d_ws, size_t ws_size,
                              hipStream_t stream) {
    const float* hidden = (const float*)d_in[0];   // 16*512*1024
    const float* mask   = (const float*)d_in[1];   // 16*512
    const float* W      = (const float*)d_in[2];   // 1024*1152
    const float* bias   = (const float*)d_in[3];   // 1152
    float* out = (float*)d_out;

    char* ws = (char*)d_ws;
    unsigned short* Ab = (unsigned short*)ws;                        // 16,777,216 B
    unsigned short* Wt = (unsigned short*)(ws + 16777216);           //  2,359,296 B
    float* sctab = (float*)(ws + 16777216 + 2359296);                //    131,072 B
    unsigned short* qk = (unsigned short*)(ws + 16777216 + 2359296 + 131072); // 18,874,368 B

    prep_kernel<<<5312, 256, 0, stream>>>(hidden, W, Ab, Wt, sctab);
    proj_rope_kernel<<<dim3(64, 9), 256, 0, stream>>>(
        Ab, Wt, bias, (const float4*)sctab, qk);
    logits_kernel<<<dim3(4, 4, BATCH * HEADS), 256, 0, stream>>>(qk, mask, out);
}